// Round 12
// baseline (196.774 us; speedup 1.0000x reference)
//
#include <hip/hip_runtime.h>
#include <hip/hip_fp16.h>
#include <hip/hip_cooperative_groups.h>
#include <math.h>

namespace cg = cooperative_groups;

#define OBJ_D 320
#define LANG_D 256
#define GEO_D 6
#define HID 256
#define NN 512
#define BATCH 2

// gelu(a) = 0.5a + a^2*q(a^2), q(t) = c*(1 - t/6), c = 1/sqrt(2*pi).
// Linear half exact in fp32 via Ci/Dj; nonlinear term (~4e-4) in f16.
#define GK0 0.3989422804014327f
#define GK1 (-0.066490380066905448f)

__device__ __forceinline__ float wave_allreduce_sum(float v) {
#pragma unroll
    for (int o = 32; o > 0; o >>= 1) v += __shfl_xor(v, o, 64);
    return v;
}
__device__ __forceinline__ float wave_allreduce_max(float v) {
#pragma unroll
    for (int o = 32; o > 0; o >>= 1) v = fmaxf(v, __shfl_xor(v, o, 64));
    return v;
}

union H2U { uint2 u; __half2 h[2]; };

// One cooperative kernel: 256 blocks x 1024 threads (1 block/CU).
// Phase A: block (b, 4 rows): l2norm + dual matmul (d split over thread
//   quarters -> 16 waves hide W-column L2 latency), redundant per-block hl,
//   hi+hl -> LDS xw2 directly (no global round-trip), hj -> f16 hj2T, Dj.
// grid.sync()
// Phase B/C: round-10 k_main body (f16 nonlinear gelu + fp32 linear part,
//   block softmax, fp32 context).
__global__ __launch_bounds__(1024) void k_fused(const float* __restrict__ emb,
                                                const float* __restrict__ geom,
                                                const float* __restrict__ utter,
                                                const float* __restrict__ W1,
                                                const float* __restrict__ b1,
                                                const float* __restrict__ W2,
                                                const float* __restrict__ b2p,
                                                float* __restrict__ emb_n,
                                                __half2* __restrict__ hj2T,
                                                float* __restrict__ Dj,
                                                float* __restrict__ out) {
    int tid = threadIdx.x;
    int w = tid >> 6, lane = tid & 63;     // w in [0,16)
    int qd = tid >> 8, h = tid & 255;      // quarter, h-index
    int blk = blockIdx.x;
    int b = blk & 1;
    int n0 = (blk >> 1) * 4;

    // ---- LDS ----
    __shared__ __half2 xw2[4][HID];            // 4 KB  {x,x}, x = hi+hl (f16)
    __shared__ __half2 w2d[HID];               // 1 KB  {64*w2}
    __shared__ __half2 scp[8][4][256];         // 32 KB f16 slice-partials
    __shared__ float4 pq4[NN];                 // 8 KB softmax weights
    __shared__ alignas(16) float part[16][4 * OBJ_D + 4];  // 82 KB (phase-C; phase-A scratch overlay)
    __shared__ float gs[4][GEO_D], rn[4];
    __shared__ float red[16], redD[4][4], redC[4][4], CiS[4];

    // phase-A overlay on `part`
    float* pool = &part[0][0];
    float4* esT4 = (float4*)pool;              // [320] f4  (floats 0..1280)
    float* esT = pool;
    float* pAI = pool + 1280;                  // [4][4][256]
    float* pAJ = pool + 5376;                  // [4][4][256]
    float* langN = pool + 9472;                // [256]
    float* lcomb = langN + 256;                // [4][256]

    // ================= PHASE A =================
    // first W prefetch group (independent of LDS)
    const float* WiC = W1 + h;
    const float* WjC = W1 + (size_t)OBJ_D * HID + h;
    int dbase = 80 * qd;
    float wi[8], wj[8], win[8], wjn[8];
#pragma unroll
    for (int k = 0; k < 8; k++) {
        wi[k] = WiC[(size_t)(dbase + k) * HID];
        wj[k] = WjC[(size_t)(dbase + k) * HID];
    }

    // stage emb rows (coalesced) into transposed LDS
    const float* esrc = emb + (size_t)(b * NN + n0) * OBJ_D;
    float ev[2]; int eidx[2]; int ecnt = 0;
    for (int idx = tid; idx < 4 * OBJ_D; idx += 1024) {
        float x = esrc[idx];
        ev[ecnt] = x; eidx[ecnt] = idx; ecnt++;
        esT[(idx % OBJ_D) * 4 + (idx / OBJ_D)] = x;
    }
    if (tid < 4 * GEO_D) gs[tid / GEO_D][tid % GEO_D] = geom[(size_t)(b * NN + n0) * GEO_D + tid];
    if (tid < 256) { float wsc = W2[tid] * 64.0f; w2d[tid] = __floats2half2_rn(wsc, wsc); }
    float uv = (tid < 256) ? utter[b * LANG_D + tid] : 0.0f;
    __syncthreads();

    // row norms (waves 0..3) + lang ss partials (same waves hold utter)
    if (w < 4) {
        float s = 0.0f;
#pragma unroll
        for (int k = lane; k < OBJ_D; k += 64) { float x = esT[k * 4 + w]; s += x * x; }
        s = wave_allreduce_sum(s);
        if (lane == 0) rn[w] = 1.0f / fmaxf(sqrtf(s), 1e-12f);
        float ls = wave_allreduce_sum(uv * uv);
        if (lane == 0) red[8 + w] = ls;
    }
    __syncthreads();
    if (tid == 0)
        red[15] = 1.0f / fmaxf(sqrtf(red[8] + red[9] + red[10] + red[11]), 1e-12f);
    // normalize emb rows, write emb_n
    float* edst = emb_n + (size_t)(b * NN + n0) * OBJ_D;
    for (int c = 0; c < ecnt; c++) {
        int idx = eidx[c];
        float nv = ev[c] * rn[idx / OBJ_D];
        esT[(idx % OBJ_D) * 4 + (idx / OBJ_D)] = nv;   // own slot
        edst[idx] = nv;
    }
    __syncthreads();
    if (tid < 256) langN[tid] = uv * red[15];

    // dual matmul over this quarter's 80 d (groups of 8, depth-1 prefetch)
    float ai[4] = {0, 0, 0, 0}, aj4[4] = {0, 0, 0, 0};
    for (int g = 0; g < 80; g += 8) {
        if (g + 8 < 80) {
#pragma unroll
            for (int k = 0; k < 8; k++) {
                win[k] = WiC[(size_t)(dbase + g + 8 + k) * HID];
                wjn[k] = WjC[(size_t)(dbase + g + 8 + k) * HID];
            }
        }
#pragma unroll
        for (int k = 0; k < 8; k++) {
            float4 e4 = esT4[dbase + g + k];
            ai[0] = fmaf(e4.x, wi[k], ai[0]); aj4[0] = fmaf(e4.x, wj[k], aj4[0]);
            ai[1] = fmaf(e4.y, wi[k], ai[1]); aj4[1] = fmaf(e4.y, wj[k], aj4[1]);
            ai[2] = fmaf(e4.z, wi[k], ai[2]); aj4[2] = fmaf(e4.z, wj[k], aj4[2]);
            ai[3] = fmaf(e4.w, wi[k], ai[3]); aj4[3] = fmaf(e4.w, wj[k], aj4[3]);
        }
#pragma unroll
        for (int k = 0; k < 8; k++) { wi[k] = win[k]; wj[k] = wjn[k]; }
    }
#pragma unroll
    for (int r = 0; r < 4; r++) {
        pAI[qd * 1024 + r * 256 + h] = ai[r];
        pAJ[qd * 1024 + r * 256 + h] = aj4[r];
    }
    __syncthreads();   // langN ready + pAI/pAJ written

    // hl partial: quarter qd covers l in [64qd, 64qd+64)
    {
        const float* Wl = W1 + (size_t)(2 * OBJ_D + GEO_D) * HID + h;
        float acc = 0.0f;
#pragma unroll 8
        for (int l = qd * 64; l < qd * 64 + 64; l++)
            acc = fmaf(langN[l], Wl[(size_t)l * HID], acc);
        lcomb[qd * 256 + h] = acc;
    }
    __syncthreads();

    // finalize (quarter 0 = 4 waves)
    if (qd == 0) {
        float hlval = b1[h] + lcomb[h] + lcomb[256 + h] + lcomb[512 + h] + lcomb[768 + h];
        float gw[GEO_D];
#pragma unroll
        for (int g = 0; g < GEO_D; g++) gw[g] = W1[(size_t)(2 * OBJ_D + g) * HID + h];
        float w2v = W2[h];
        float yi[4], vj[4];
#pragma unroll
        for (int r = 0; r < 4; r++) {
            float A = pAI[r * 256 + h] + pAI[1024 + r * 256 + h] +
                      pAI[2048 + r * 256 + h] + pAI[3072 + r * 256 + h];
            float J = pAJ[r * 256 + h] + pAJ[1024 + r * 256 + h] +
                      pAJ[2048 + r * 256 + h] + pAJ[3072 + r * 256 + h];
            float gp = 0.0f;
#pragma unroll
            for (int g = 0; g < GEO_D; g++) gp = fmaf(gs[r][g], gw[g], gp);
            yi[r] = A - gp;
            vj[r] = J + gp;
            float x = yi[r] + hlval;
            xw2[r][h] = __floats2half2_rn(x, x);   // hi+hl straight to LDS
        }
        {
            __half2 p0 = __floats2half2_rn(vj[0], vj[1]);
            __half2 p1 = __floats2half2_rn(vj[2], vj[3]);
            __half2* dst = hj2T + ((size_t)(b * 256 + h) * 256 + (n0 >> 1));
            dst[0] = p0;
            dst[1] = p1;
        }
#pragma unroll
        for (int r = 0; r < 4; r++) {
            float ds = wave_allreduce_sum(w2v * vj[r]);
            float cs = wave_allreduce_sum(w2v * yi[r]);
            if (lane == 0) { redD[w][r] = ds; redC[w][r] = cs; }
        }
        float cl = wave_allreduce_sum(w2v * hlval);
        if (lane == 0) red[w] = cl;
    }
    __syncthreads();
    if (tid < 4) {
        Dj[b * NN + n0 + tid] = redD[0][tid] + redD[1][tid] + redD[2][tid] + redD[3][tid];
        float Chl = (red[0] + red[1] + red[2] + red[3]) * 0.25f;  // each wave summed full h? no:
        // red[w] = sum over lane-h of wave w (h = w*64+lane) -> the four partials sum to full Chl
        Chl = red[0] + red[1] + red[2] + red[3];
        CiS[tid] = redC[0][tid] + redC[1][tid] + redC[2][tid] + redC[3][tid] + Chl;
    }
    __threadfence();
    cg::this_grid().sync();

    // ================= PHASE B: scores =================
    int s = w >> 1;                      // h-slice [32s, 32s+32)
    int rg = w & 1;                      // j-half
    const uint2* hjq = (const uint2*)(hj2T + (size_t)b * 256 * 256) + (64 * rg + lane);
    int h0 = s * 32;
    H2U v[8], vn[8];
#pragma unroll
    for (int k = 0; k < 8; k++) v[k].u = hjq[(size_t)(h0 + k) * 128];

    const __half2 K0h = __floats2half2_rn(GK0, GK0);
    const __half2 K1h = __floats2half2_rn(GK1, GK1);
    __half2 acc2[4][2];
#pragma unroll
    for (int r = 0; r < 4; r++)
#pragma unroll
        for (int q = 0; q < 2; q++) acc2[r][q] = __floats2half2_rn(0.0f, 0.0f);

    for (int g = 0; g < 4; g++) {
        if (g + 1 < 4) {
#pragma unroll
            for (int k = 0; k < 8; k++) vn[k].u = hjq[(size_t)(h0 + (g + 1) * 8 + k) * 128];
        }
#pragma unroll
        for (int k = 0; k < 8; k++) {
            int hh = h0 + g * 8 + k;
            __half2 x0 = xw2[0][hh], x1 = xw2[1][hh], x2 = xw2[2][hh], x3 = xw2[3][hh];
            __half2 ww = w2d[hh];
#pragma unroll
            for (int q = 0; q < 2; q++) {
                __half2 vv = v[k].h[q];
                __half2 a0 = __hadd2(vv, x0), a1 = __hadd2(vv, x1);
                __half2 a2 = __hadd2(vv, x2), a3 = __hadd2(vv, x3);
                __half2 t0 = __hmul2(a0, a0), t1 = __hmul2(a1, a1);
                __half2 t2 = __hmul2(a2, a2), t3 = __hmul2(a3, a3);
                __half2 q0 = __hfma2(t0, K1h, K0h), q1 = __hfma2(t1, K1h, K0h);
                __half2 q2 = __hfma2(t2, K1h, K0h), q3 = __hfma2(t3, K1h, K0h);
                __half2 m0 = __hmul2(t0, q0), m1 = __hmul2(t1, q1);
                __half2 m2 = __hmul2(t2, q2), m3 = __hmul2(t3, q3);
                acc2[0][q] = __hfma2(m0, ww, acc2[0][q]);
                acc2[1][q] = __hfma2(m1, ww, acc2[1][q]);
                acc2[2][q] = __hfma2(m2, ww, acc2[2][q]);
                acc2[3][q] = __hfma2(m3, ww, acc2[3][q]);
            }
        }
#pragma unroll
        for (int k = 0; k < 8; k++) v[k] = vn[k];
    }
    {
        int jp0 = 128 * rg + 2 * lane;
#pragma unroll
        for (int r = 0; r < 4; r++) {
            H2U o; o.h[0] = acc2[r][0]; o.h[1] = acc2[r][1];
            *(uint2*)&scp[s][r][jp0] = o.u;
        }
    }
    float Ci[4];
#pragma unroll
    for (int r = 0; r < 4; r++) Ci[r] = CiS[r];
    __syncthreads();

    // combine slices + linear part + block softmax (tid<256 = j-pairs)
    const float inv64 = 1.0f / 64.0f;
    float cs2[4][2];
    if (tid < 256) {
        int jp = tid;
        float2 dj2 = ((const float2*)Dj)[b * 256 + jp];
#pragma unroll
        for (int r = 0; r < 4; r++) {
            float lo = 0.0f, hi = 0.0f;
#pragma unroll
            for (int s8 = 0; s8 < 8; s8++) {
                float2 f = __half22float2(scp[s8][r][jp]);
                lo += f.x; hi += f.y;
            }
            cs2[r][0] = lo * inv64 + 0.5f * (Ci[r] + dj2.x);
            cs2[r][1] = hi * inv64 + 0.5f * (Ci[r] + dj2.y);
        }
#pragma unroll
        for (int r = 0; r < 4; r++) {
            float m = wave_allreduce_max(fmaxf(cs2[r][0], cs2[r][1]));
            if (lane == 0) redD[w][r] = m;     // reuse redD as redx
        }
    }
    __syncthreads();
    float M[4];
#pragma unroll
    for (int r = 0; r < 4; r++)
        M[r] = fmaxf(fmaxf(redD[0][r], redD[1][r]), fmaxf(redD[2][r], redD[3][r]));
    float ex[4][2];
    if (tid < 256) {
#pragma unroll
        for (int r = 0; r < 4; r++) {
            ex[r][0] = expf(cs2[r][0] - M[r]);
            ex[r][1] = expf(cs2[r][1] - M[r]);
            float qs = wave_allreduce_sum(ex[r][0] + ex[r][1]);
            float qd2 = wave_allreduce_sum(ex[r][0] * cs2[r][0] + ex[r][1] * cs2[r][1]);
            if (lane == 0) { redC[w][r] = qs; red[4 * w + r] = qd2; }  // reuse
        }
    }
    __syncthreads();
    float inv[4];
#pragma unroll
    for (int r = 0; r < 4; r++) {
        float S = redC[0][r] + redC[1][r] + redC[2][r] + redC[3][r];
        inv[r] = 1.0f / S;
    }
    if (tid < 256) {
        int p = tid;
        float4 pa, pb;
        pa.x = ex[0][0] * inv[0]; pa.y = ex[1][0] * inv[1];
        pa.z = ex[2][0] * inv[2]; pa.w = ex[3][0] * inv[3];
        pb.x = ex[0][1] * inv[0]; pb.y = ex[1][1] * inv[1];
        pb.z = ex[2][1] * inv[2]; pb.w = ex[3][1] * inv[3];
        pq4[2 * p] = pa;
        pq4[2 * p + 1] = pb;
    }
    if (tid == 0) {
        float b2 = b2p[0];
#pragma unroll
        for (int r = 0; r < 4; r++) {
            float D = red[r] + red[4 + r] + red[8 + r] + red[12 + r];
            out[b * NN + n0 + r] = D * inv[r] + b2;
        }
    }
    __syncthreads();

    // ================= PHASE C: context =================
    const float* eb = emb_n + (size_t)b * NN * OBJ_D;
    float ac[4][5];
#pragma unroll
    for (int r = 0; r < 4; r++)
#pragma unroll
        for (int c = 0; c < 5; c++) ac[r][c] = 0.0f;
    int jbase = w * 32;
#pragma unroll 4
    for (int jj = 0; jj < 32; jj++) {
        float4 qq = pq4[jbase + jj];
        const float* e = eb + (size_t)(jbase + jj) * OBJ_D + lane;
#pragma unroll
        for (int c = 0; c < 5; c++) {
            float evv = e[64 * c];
            ac[0][c] = fmaf(qq.x, evv, ac[0][c]);
            ac[1][c] = fmaf(qq.y, evv, ac[1][c]);
            ac[2][c] = fmaf(qq.z, evv, ac[2][c]);
            ac[3][c] = fmaf(qq.w, evv, ac[3][c]);
        }
    }
#pragma unroll
    for (int r = 0; r < 4; r++)
#pragma unroll
        for (int c = 0; c < 5; c++) part[w][r * OBJ_D + c * 64 + lane] = ac[r][c];
    __syncthreads();

    for (int item = tid; item < 4 * OBJ_D; item += 1024) {
        float ssum = 0.0f;
#pragma unroll
        for (int ww2 = 0; ww2 < 16; ww2++) ssum += part[ww2][item];
        int r = item / OBJ_D, d = item - r * OBJ_D;
        out[BATCH * NN + (size_t)(b * NN + n0 + r) * OBJ_D + d] = ssum;
    }
}

extern "C" void kernel_launch(void* const* d_in, const int* in_sizes, int n_in,
                              void* d_out, int out_size, void* d_ws, size_t ws_size,
                              hipStream_t stream) {
    const float* emb   = (const float*)d_in[0];
    const float* geom  = (const float*)d_in[1];
    const float* utter = (const float*)d_in[2];
    const float* W1    = (const float*)d_in[3];
    const float* b1    = (const float*)d_in[4];
    const float* W2    = (const float*)d_in[5];
    const float* b2    = (const float*)d_in[6];
    float* out = (float*)d_out;

    float* ws = (float*)d_ws;
    float* emb_n = ws;                                // BATCH*NN*OBJ_D
    float* hj2f  = emb_n + BATCH * NN * OBJ_D;        // BATCH*256*256 half2
    float* Djp   = hj2f + BATCH * 256 * 256;          // BATCH*NN
    __half2* hj2T = (__half2*)hj2f;

    void* args[] = {(void*)&emb, (void*)&geom, (void*)&utter, (void*)&W1,
                    (void*)&b1, (void*)&W2, (void*)&b2,
                    (void*)&emb_n, (void*)&hj2T, (void*)&Djp, (void*)&out};
    hipLaunchCooperativeKernel((const void*)k_fused, dim3(256), dim3(1024),
                               args, 0, stream);
}

// Round 13
// 107.674 us; speedup vs baseline: 1.8275x; 1.8275x over previous
//
#include <hip/hip_runtime.h>
#include <hip/hip_fp16.h>
#include <math.h>

#define OBJ_D 320
#define LANG_D 256
#define GEO_D 6
#define HID 256
#define NN 512
#define BATCH 2

// gelu(a) = 0.5a + a^2*q(a^2), q(t) = c*(1 - t/6), c = 1/sqrt(2*pi).
// Linear half exact in fp32 via Ci/Dj; nonlinear term (~4e-4) in f16.
#define GK0 0.3989422804014327f
#define GK1 (-0.066490380066905448f)

__device__ __forceinline__ float wave_allreduce_sum(float v) {
#pragma unroll
    for (int o = 32; o > 0; o >>= 1) v += __shfl_xor(v, o, 64);
    return v;
}
__device__ __forceinline__ float wave_allreduce_max(float v) {
#pragma unroll
    for (int o = 32; o > 0; o >>= 1) v = fmaxf(v, __shfl_xor(v, o, 64));
    return v;
}

// k_pre (256 threads, R10 structure): blocks 0..255 = fused l2norm + dual
// matmul + Dj/Ci + f16 j-pair repack + f16 emb pairs (ctx input; fp32 emb_n
// dropped — ctx was its only consumer). Blocks 256..257 = lang norm + hl + Chl.
__global__ __launch_bounds__(256) void k_pre(const float* __restrict__ emb,
                                             const float* __restrict__ geom,
                                             const float* __restrict__ utter,
                                             const float* __restrict__ W1,
                                             const float* __restrict__ b1,
                                             const float* __restrict__ W2,
                                             __half2* __restrict__ emb_h,
                                             float* __restrict__ hi_p,
                                             __half2* __restrict__ hj2T,
                                             float* __restrict__ hl,
                                             float* __restrict__ Dj,
                                             float* __restrict__ Cip,
                                             float* __restrict__ Chl) {
    int tid = threadIdx.x;
    int wid = tid >> 6, lane = tid & 63;

    __shared__ float4 esT4[OBJ_D];
    __shared__ float gs[4][GEO_D];
    __shared__ float rn[4];
    __shared__ float lang_s[LANG_D];
    __shared__ float red[8];
    __shared__ float redD[4][4], redC[4][4];
    float* esT = (float*)esT4;

    if (blockIdx.x >= 256) {
        int b = blockIdx.x - 256;
        float v = utter[b * LANG_D + tid];
        float ss = wave_allreduce_sum(v * v);
        if (lane == 0) red[wid] = ss;
        __syncthreads();
        if (tid == 0) red[0] = 1.0f / fmaxf(sqrtf(red[0] + red[1] + red[2] + red[3]), 1e-12f);
        __syncthreads();
        lang_s[tid] = v * red[0];
        __syncthreads();
        const float* Wl = W1 + (size_t)(2 * OBJ_D + GEO_D) * HID + tid;
        float acc = b1[tid];
#pragma unroll 8
        for (int l = 0; l < LANG_D; l++) acc = fmaf(lang_s[l], Wl[(size_t)l * HID], acc);
        hl[b * HID + tid] = acc;
        float cpart = wave_allreduce_sum(W2[tid] * acc);
        __syncthreads();
        if (lane == 0) red[wid] = cpart;
        __syncthreads();
        if (tid == 0) Chl[b] = red[0] + red[1] + red[2] + red[3];
        return;
    }

    const int R = 4;
    int b = blockIdx.x & 1;
    int n0 = (blockIdx.x >> 1) * R;

    const float* WiC = W1 + tid;
    const float* WjC = W1 + (size_t)OBJ_D * HID + tid;
    float wi[16], wj[16], win[16], wjn[16];
#pragma unroll
    for (int k = 0; k < 16; k++) {
        wi[k] = WiC[(size_t)k * HID];
        wj[k] = WjC[(size_t)k * HID];
    }

    const float* esrc = emb + (size_t)(b * NN + n0) * OBJ_D;
    float ev[5]; int er[5], ed[5];
#pragma unroll
    for (int k = 0; k < 5; k++) {
        int idx = k * 256 + tid;
        ev[k] = esrc[idx];
        er[k] = idx / OBJ_D; ed[k] = idx % OBJ_D;
        esT[ed[k] * 4 + er[k]] = ev[k];
    }
    if (tid < R * GEO_D) gs[tid / GEO_D][tid % GEO_D] = geom[(size_t)(b * NN + n0) * GEO_D + tid];
    __syncthreads();
    {
        float s = 0.0f;
#pragma unroll
        for (int k = lane; k < OBJ_D; k += 64) { float x = esT[k * 4 + wid]; s += x * x; }
        s = wave_allreduce_sum(s);
        if (lane == 0) rn[wid] = 1.0f / fmaxf(sqrtf(s), 1e-12f);
    }
    __syncthreads();
#pragma unroll
    for (int k = 0; k < 5; k++) {
        float nv = ev[k] * rn[er[k]];
        esT[ed[k] * 4 + er[k]] = nv;   // own slot
    }
    __syncthreads();

    // f16 emb pairs for ctx: emb_h[(b*NN+n0+r)*160 + p] = {e[2p], e[2p+1]}
    for (int idx = tid; idx < R * 160; idx += 256) {
        int r = idx / 160, p = idx - r * 160;
        float a = esT[(2 * p) * 4 + r];
        float c = esT[(2 * p + 1) * 4 + r];
        emb_h[(size_t)(b * NN + n0 + r) * 160 + p] = __floats2half2_rn(a, c);
    }

    float ai[R] = {0, 0, 0, 0}, aj[R] = {0, 0, 0, 0};
    for (int d0 = 0; d0 < OBJ_D; d0 += 16) {
        if (d0 + 16 < OBJ_D) {
#pragma unroll
            for (int k = 0; k < 16; k++) {
                win[k] = WiC[(size_t)(d0 + 16 + k) * HID];
                wjn[k] = WjC[(size_t)(d0 + 16 + k) * HID];
            }
        }
#pragma unroll
        for (int k = 0; k < 16; k++) {
            float4 e4 = esT4[d0 + k];
            ai[0] = fmaf(e4.x, wi[k], ai[0]); aj[0] = fmaf(e4.x, wj[k], aj[0]);
            ai[1] = fmaf(e4.y, wi[k], ai[1]); aj[1] = fmaf(e4.y, wj[k], aj[1]);
            ai[2] = fmaf(e4.z, wi[k], ai[2]); aj[2] = fmaf(e4.z, wj[k], aj[2]);
            ai[3] = fmaf(e4.w, wi[k], ai[3]); aj[3] = fmaf(e4.w, wj[k], aj[3]);
        }
#pragma unroll
        for (int k = 0; k < 16; k++) { wi[k] = win[k]; wj[k] = wjn[k]; }
    }

    float gw[GEO_D];
#pragma unroll
    for (int g = 0; g < GEO_D; g++) gw[g] = W1[(size_t)(2 * OBJ_D + g) * HID + tid];
    float w2v = W2[tid];
    float yi[R], vj[R];
#pragma unroll
    for (int r = 0; r < R; r++) {
        float gp = 0.0f;
#pragma unroll
        for (int g = 0; g < GEO_D; g++) gp = fmaf(gs[r][g], gw[g], gp);
        yi[r] = ai[r] - gp;
        vj[r] = aj[r] + gp;
        hi_p[(size_t)(b * NN + n0 + r) * HID + tid] = yi[r];
    }
    {
        __half2 p0 = __floats2half2_rn(vj[0], vj[1]);
        __half2 p1 = __floats2half2_rn(vj[2], vj[3]);
        __half2* dst = hj2T + ((size_t)(b * 256 + tid) * 256 + (n0 >> 1));
        dst[0] = p0;
        dst[1] = p1;
    }
#pragma unroll
    for (int r = 0; r < R; r++) {
        float ds = wave_allreduce_sum(w2v * vj[r]);
        float cs = wave_allreduce_sum(w2v * yi[r]);
        if (lane == 0) { redD[wid][r] = ds; redC[wid][r] = cs; }
    }
    __syncthreads();
    if (tid < R) {
        Dj[b * NN + n0 + tid]  = redD[0][tid] + redD[1][tid] + redD[2][tid] + redD[3][tid];
        Cip[b * NN + n0 + tid] = redC[0][tid] + redC[1][tid] + redC[2][tid] + redC[3][tid];
    }
}

union H2U { uint2 u; __half2 h[2]; };
union H2x4 { uint4 u4; __half2 h2[4]; };

// k_main (R10 structure + b128 LDS score reads + f16 ctx):
// block = (b, 4 i-rows), 1024 threads, grid 256.
__global__ __launch_bounds__(1024) void k_main(const float* __restrict__ hi_p,
                                               const __half2* __restrict__ hj2T,
                                               const __half2* __restrict__ emb_h,
                                               const float* __restrict__ hl,
                                               const float* __restrict__ W2,
                                               const float* __restrict__ b2p,
                                               const float* __restrict__ Dj,
                                               const float* __restrict__ Cip,
                                               const float* __restrict__ Chl,
                                               float* __restrict__ out) {
    int b = blockIdx.x & 1;
    int i0 = (blockIdx.x >> 1) * 4;
    int tid = threadIdx.x;
    int w = tid >> 6, lane = tid & 63;   // w in [0,16)
    int s = w >> 1;                      // h-slice [32s, 32s+32)
    int rg = w & 1;                      // j-half

    __shared__ alignas(16) __half2 xw2[4][HID];
    __shared__ alignas(16) __half2 w2d[HID];
    __shared__ __half2 scp[8][4][256];
    __shared__ float4 pq4[NN];
    __shared__ alignas(16) float part[16][4 * OBJ_D + 4];
    __shared__ float redx[4][4], redsum[4][4], reddot[4][4];

    const uint2* hjq = (const uint2*)(hj2T + (size_t)b * 256 * 256) + (64 * rg + lane);
    int h0 = s * 32;
    H2U v[8], vn[8];
#pragma unroll
    for (int k = 0; k < 8; k++) v[k].u = hjq[(size_t)(h0 + k) * 128];

    for (int idx = tid; idx < 5 * HID; idx += 1024) {
        int r = idx >> 8, h = idx & 255;
        if (r < 4) {
            float x = hi_p[(size_t)(b * NN + i0 + r) * HID + h] + hl[b * HID + h];
            xw2[r][h] = __floats2half2_rn(x, x);
        } else {
            float wsc = W2[h] * 64.0f;
            w2d[h] = __floats2half2_rn(wsc, wsc);
        }
    }
    __syncthreads();

    const __half2 K0h = __floats2half2_rn(GK0, GK0);
    const __half2 K1h = __floats2half2_rn(GK1, GK1);
    __half2 acc2[4][2];
#pragma unroll
    for (int r = 0; r < 4; r++)
#pragma unroll
        for (int q = 0; q < 2; q++) acc2[r][q] = __floats2half2_rn(0.0f, 0.0f);

    for (int g = 0; g < 4; g++) {
        if (g + 1 < 4) {
#pragma unroll
            for (int k = 0; k < 8; k++) vn[k].u = hjq[(size_t)(h0 + (g + 1) * 8 + k) * 128];
        }
#pragma unroll
        for (int c4 = 0; c4 < 2; c4++) {
            int hb = h0 + g * 8 + c4 * 4;
            H2x4 X0, X1, X2, X3, WW;                  // b128 LDS reads (4 h each)
            X0.u4 = *(const uint4*)&xw2[0][hb];
            X1.u4 = *(const uint4*)&xw2[1][hb];
            X2.u4 = *(const uint4*)&xw2[2][hb];
            X3.u4 = *(const uint4*)&xw2[3][hb];
            WW.u4 = *(const uint4*)&w2d[hb];
#pragma unroll
            for (int kk = 0; kk < 4; kk++) {
                int k = c4 * 4 + kk;
                __half2 ww = WW.h2[kk];
                __half2 x0 = X0.h2[kk], x1 = X1.h2[kk], x2 = X2.h2[kk], x3 = X3.h2[kk];
#pragma unroll
                for (int q = 0; q < 2; q++) {
                    __half2 vv = v[k].h[q];
                    __half2 a0 = __hadd2(vv, x0), a1 = __hadd2(vv, x1);
                    __half2 a2 = __hadd2(vv, x2), a3 = __hadd2(vv, x3);
                    __half2 t0 = __hmul2(a0, a0), t1 = __hmul2(a1, a1);
                    __half2 t2 = __hmul2(a2, a2), t3 = __hmul2(a3, a3);
                    __half2 q0 = __hfma2(t0, K1h, K0h), q1 = __hfma2(t1, K1h, K0h);
                    __half2 q2 = __hfma2(t2, K1h, K0h), q3 = __hfma2(t3, K1h, K0h);
                    __half2 m0 = __hmul2(t0, q0), m1 = __hmul2(t1, q1);
                    __half2 m2 = __hmul2(t2, q2), m3 = __hmul2(t3, q3);
                    acc2[0][q] = __hfma2(m0, ww, acc2[0][q]);
                    acc2[1][q] = __hfma2(m1, ww, acc2[1][q]);
                    acc2[2][q] = __hfma2(m2, ww, acc2[2][q]);
                    acc2[3][q] = __hfma2(m3, ww, acc2[3][q]);
                }
            }
        }
#pragma unroll
        for (int k = 0; k < 8; k++) v[k] = vn[k];
    }
    {
        int jp0 = 128 * rg + 2 * lane;
#pragma unroll
        for (int r = 0; r < 4; r++) {
            H2U o; o.h[0] = acc2[r][0]; o.h[1] = acc2[r][1];
            *(uint2*)&scp[s][r][jp0] = o.u;
        }
    }

    float Ci[4];
#pragma unroll
    for (int r = 0; r < 4; r++) Ci[r] = Cip[b * NN + i0 + r] + Chl[b];
    __syncthreads();

    const float inv64 = 1.0f / 64.0f;
    float cs[4][2];
    if (tid < 256) {
        int jp = tid;
        float2 dj2 = ((const float2*)Dj)[b * 256 + jp];
#pragma unroll
        for (int r = 0; r < 4; r++) {
            float lo = 0.0f, hi = 0.0f;
#pragma unroll
            for (int s8 = 0; s8 < 8; s8++) {
                float2 f = __half22float2(scp[s8][r][jp]);
                lo += f.x; hi += f.y;
            }
            cs[r][0] = lo * inv64 + 0.5f * (Ci[r] + dj2.x);
            cs[r][1] = hi * inv64 + 0.5f * (Ci[r] + dj2.y);
        }
#pragma unroll
        for (int r = 0; r < 4; r++) {
            float m = wave_allreduce_max(fmaxf(cs[r][0], cs[r][1]));
            if (lane == 0) redx[w][r] = m;
        }
    }
    __syncthreads();
    float M[4];
#pragma unroll
    for (int r = 0; r < 4; r++)
        M[r] = fmaxf(fmaxf(redx[0][r], redx[1][r]), fmaxf(redx[2][r], redx[3][r]));
    float ex[4][2];
    if (tid < 256) {
#pragma unroll
        for (int r = 0; r < 4; r++) {
            ex[r][0] = expf(cs[r][0] - M[r]);
            ex[r][1] = expf(cs[r][1] - M[r]);
            float qs = wave_allreduce_sum(ex[r][0] + ex[r][1]);
            float qd = wave_allreduce_sum(ex[r][0] * cs[r][0] + ex[r][1] * cs[r][1]);
            if (lane == 0) { redsum[w][r] = qs; reddot[w][r] = qd; }
        }
    }
    __syncthreads();
    float inv[4];
#pragma unroll
    for (int r = 0; r < 4; r++) {
        float S = redsum[0][r] + redsum[1][r] + redsum[2][r] + redsum[3][r];
        inv[r] = 1.0f / S;
    }
    if (tid < 256) {
        int p = tid;
        float4 pa, pb;
        pa.x = ex[0][0] * inv[0]; pa.y = ex[1][0] * inv[1];
        pa.z = ex[2][0] * inv[2]; pa.w = ex[3][0] * inv[3];
        pb.x = ex[0][1] * inv[0]; pb.y = ex[1][1] * inv[1];
        pb.z = ex[2][1] * inv[2]; pb.w = ex[3][1] * inv[3];
        pq4[2 * p] = pa;
        pq4[2 * p + 1] = pb;
    }
    if (tid == 0) {
        float b2 = b2p[0];
#pragma unroll
        for (int r = 0; r < 4; r++) {
            float D = reddot[0][r] + reddot[1][r] + reddot[2][r] + reddot[3][r];
            out[b * NN + i0 + r] = D * inv[r] + b2;
        }
    }
    __syncthreads();

    // ---- context: f16 emb pairs; wave w owns j in [32w, 32w+32) ----
    const __half2* ebh = emb_h + (size_t)b * NN * 160;
    float2 ac[4][3];
#pragma unroll
    for (int r = 0; r < 4; r++)
#pragma unroll
        for (int c = 0; c < 3; c++) { ac[r][c].x = 0.0f; ac[r][c].y = 0.0f; }
    int jbase = w * 32;
    bool has2 = (lane < 32);
    int off2 = has2 ? (128 + lane) : lane;   // clamp to stay in-bounds
#pragma unroll 4
    for (int jj = 0; jj < 32; jj++) {
        float4 qq = pq4[jbase + jj];
        const __half2* e = ebh + (size_t)(jbase + jj) * 160;
        float2 f0 = __half22float2(e[lane]);
        float2 f1 = __half22float2(e[64 + lane]);
        float2 f2 = __half22float2(e[off2]);
        float qr[4] = {qq.x, qq.y, qq.z, qq.w};
#pragma unroll
        for (int r = 0; r < 4; r++) {
            float p = qr[r];
            ac[r][0].x = fmaf(p, f0.x, ac[r][0].x);
            ac[r][0].y = fmaf(p, f0.y, ac[r][0].y);
            ac[r][1].x = fmaf(p, f1.x, ac[r][1].x);
            ac[r][1].y = fmaf(p, f1.y, ac[r][1].y);
            ac[r][2].x = fmaf(p, f2.x, ac[r][2].x);
            ac[r][2].y = fmaf(p, f2.y, ac[r][2].y);
        }
    }
#pragma unroll
    for (int r = 0; r < 4; r++) {
        *(float2*)&part[w][r * OBJ_D + 2 * lane] = ac[r][0];
        *(float2*)&part[w][r * OBJ_D + 128 + 2 * lane] = ac[r][1];
        if (has2) *(float2*)&part[w][r * OBJ_D + 256 + 2 * lane] = ac[r][2];
    }
    __syncthreads();

    for (int item = tid; item < 4 * OBJ_D; item += 1024) {
        float ssum = 0.0f;
#pragma unroll
        for (int ww2 = 0; ww2 < 16; ww2++) ssum += part[ww2][item];
        int r = item / OBJ_D, d = item - r * OBJ_D;
        out[BATCH * NN + (size_t)(b * NN + i0 + r) * OBJ_D + d] = ssum;
    }
}

extern "C" void kernel_launch(void* const* d_in, const int* in_sizes, int n_in,
                              void* d_out, int out_size, void* d_ws, size_t ws_size,
                              hipStream_t stream) {
    const float* emb   = (const float*)d_in[0];
    const float* geom  = (const float*)d_in[1];
    const float* utter = (const float*)d_in[2];
    const float* W1    = (const float*)d_in[3];
    const float* b1    = (const float*)d_in[4];
    const float* W2    = (const float*)d_in[5];
    const float* b2    = (const float*)d_in[6];
    float* out = (float*)d_out;

    float* ws = (float*)d_ws;
    float* hl    = ws;                                // BATCH*HID = 512
    float* hi_p  = ws + 512;                          // BATCH*NN*HID
    float* hj2f  = hi_p + BATCH * NN * HID;           // BATCH*256*256 half2
    float* Dj    = hj2f + BATCH * 256 * 256;          // BATCH*NN
    float* Cip   = Dj + BATCH * NN;                   // BATCH*NN
    float* Chl   = Cip + BATCH * NN;                  // BATCH
    __half2* emb_h = (__half2*)(Chl + BATCH);         // BATCH*NN*160 half2
    __half2* hj2T = (__half2*)hj2f;

    hipLaunchKernelGGL(k_pre, dim3(256 + BATCH), dim3(256), 0, stream,
                       emb, geom, utter, W1, b1, W2, emb_h, hi_p, hj2T, hl, Dj, Cip, Chl);
    hipLaunchKernelGGL(k_main, dim3(BATCH * NN / 4), dim3(1024), 0, stream,
                       hi_p, hj2T, emb_h, hl, W2, b2, Dj, Cip, Chl, out);
}